// Round 1
// baseline (440.412 us; speedup 1.0000x reference)
//
#include <hip/hip_runtime.h>
#include <stdint.h>

// ---------------------------------------------------------------------------
// Attention_18116172054662 on MI355X (gfx950)
//   L = tgt @ src^T  (per batch, split-bf16 triple MFMA for f32-grade logits)
//   weight = softmax(L, axis=tgt)   -> second output (f32, in place in d_out)
//   weight_sum = weight @ src       (bf16 MFMA, NT via pre-transposed src)
//   out = [weight_sum | tgt] @ W^T + b   (bf16 MFMA NT)
// ---------------------------------------------------------------------------

#define B_   4
#define S_   2048
#define D_   1024
#define OUTD 1024
#define K2   2048   // 2*D

typedef unsigned short ushort_t;
typedef __bf16 bf16x8 __attribute__((ext_vector_type(8)));
typedef float  f32x4  __attribute__((ext_vector_type(4)));

__device__ __forceinline__ ushort_t f2bf(float f) {
    uint32_t u = __float_as_uint(f);
    uint32_t r = (u + 0x7FFFu + ((u >> 16) & 1u)) >> 16;   // RNE
    return (ushort_t)r;
}
__device__ __forceinline__ float bf2f(ushort_t h) {
    return __uint_as_float(((uint32_t)h) << 16);
}

// --------------------------- elementwise prep ------------------------------

// split src/tgt into bf16 hi/lo; also drop tgt_hi into A_cat[:,1024:2048]
__global__ void k_split(const float* __restrict__ src, const float* __restrict__ tgt,
                        ushort_t* __restrict__ sh, ushort_t* __restrict__ sl,
                        ushort_t* __restrict__ th, ushort_t* __restrict__ tl,
                        ushort_t* __restrict__ acat)
{
    const int64_t n = (int64_t)B_ * S_ * D_;
    for (int64_t i = (int64_t)blockIdx.x * blockDim.x + threadIdx.x; i < n;
         i += (int64_t)gridDim.x * blockDim.x) {
        float s = src[i];
        ushort_t hs = f2bf(s);
        sh[i] = hs;
        sl[i] = f2bf(s - bf2f(hs));
        float t = tgt[i];
        ushort_t ht = f2bf(t);
        th[i] = ht;
        tl[i] = f2bf(t - bf2f(ht));
        int64_t row = i >> 10;          // D_ = 1024
        int     d   = (int)(i & 1023);
        acat[row * K2 + D_ + d] = ht;
    }
}

__global__ void k_wconv(const float* __restrict__ W, ushort_t* __restrict__ wb)
{
    const int64_t n = (int64_t)OUTD * K2;
    for (int64_t i = (int64_t)blockIdx.x * blockDim.x + threadIdx.x; i < n;
         i += (int64_t)gridDim.x * blockDim.x)
        wb[i] = f2bf(W[i]);
}

// srcT[b,d,s] = bf16(src[b,s,d])  (for the NT form of GEMM2)
__global__ void k_transpose(const float* __restrict__ src, ushort_t* __restrict__ sT)
{
    __shared__ ushort_t tile[32][33];
    int b  = blockIdx.z;
    int d0 = blockIdx.x * 32, s0 = blockIdx.y * 32;
    int tx = threadIdx.x, ty = threadIdx.y;   // block (32,8)
#pragma unroll
    for (int i = 0; i < 4; i++) {
        int s = s0 + ty + i * 8;
        tile[ty + i * 8][tx] = f2bf(src[((int64_t)b * S_ + s) * D_ + d0 + tx]);
    }
    __syncthreads();
#pragma unroll
    for (int i = 0; i < 4; i++) {
        int d = d0 + ty + i * 8;
        sT[((int64_t)b * D_ + d) * S_ + s0 + tx] = tile[tx][ty + i * 8];
    }
}

// ------------------------------- GEMM 1 ------------------------------------
// L[b] = tgt[b] @ src[b]^T with split-bf16:  Ah*Bh + Ah*Bl + Al*Bh
// 128x128 tile, BK=32, 256 threads = 4 waves in 2x2, 16x16x32 bf16 MFMA.
__launch_bounds__(256)
__global__ void k_gemm_logits(const ushort_t* __restrict__ Ah, const ushort_t* __restrict__ Al,
                              const ushort_t* __restrict__ Bh, const ushort_t* __restrict__ Bl,
                              float* __restrict__ C)
{
    const int M = S_, N = S_, K = D_;
    int b = blockIdx.z;
    Ah += (int64_t)b * M * K;  Al += (int64_t)b * M * K;
    Bh += (int64_t)b * N * K;  Bl += (int64_t)b * N * K;
    C  += (int64_t)b * M * N;

    __shared__ __align__(16) ushort_t sAh[128 * 32], sAl[128 * 32];
    __shared__ __align__(16) ushort_t sBh[128 * 32], sBl[128 * 32];

    int t    = threadIdx.x;
    int m0   = blockIdx.y * 128, n0 = blockIdx.x * 128;
    int wave = t >> 6, lane = t & 63;
    int wr   = (wave >> 1) * 64, wc = (wave & 1) * 64;
    int l15  = lane & 15, quad = lane >> 4;

    f32x4 acc[4][4];
#pragma unroll
    for (int i = 0; i < 4; i++)
#pragma unroll
        for (int j = 0; j < 4; j++) acc[i][j] = (f32x4){0.f, 0.f, 0.f, 0.f};

    int srow = t >> 2;          // 0..63
    int scol = (t & 3) * 8;     // 0/8/16/24 (bf16)

    for (int k0 = 0; k0 < K; k0 += 32) {
        // stage 4 tiles (2 x 16B rows per thread per tile)
        *(uint4*)(&sAh[srow * 32 + scol])        = *(const uint4*)(Ah + (int64_t)(m0 + srow) * K + k0 + scol);
        *(uint4*)(&sAh[(srow + 64) * 32 + scol]) = *(const uint4*)(Ah + (int64_t)(m0 + srow + 64) * K + k0 + scol);
        *(uint4*)(&sAl[srow * 32 + scol])        = *(const uint4*)(Al + (int64_t)(m0 + srow) * K + k0 + scol);
        *(uint4*)(&sAl[(srow + 64) * 32 + scol]) = *(const uint4*)(Al + (int64_t)(m0 + srow + 64) * K + k0 + scol);
        *(uint4*)(&sBh[srow * 32 + scol])        = *(const uint4*)(Bh + (int64_t)(n0 + srow) * K + k0 + scol);
        *(uint4*)(&sBh[(srow + 64) * 32 + scol]) = *(const uint4*)(Bh + (int64_t)(n0 + srow + 64) * K + k0 + scol);
        *(uint4*)(&sBl[srow * 32 + scol])        = *(const uint4*)(Bl + (int64_t)(n0 + srow) * K + k0 + scol);
        *(uint4*)(&sBl[(srow + 64) * 32 + scol]) = *(const uint4*)(Bl + (int64_t)(n0 + srow + 64) * K + k0 + scol);
        __syncthreads();

        bf16x8 ah[4], al[4], bh[4], bl[4];
#pragma unroll
        for (int i = 0; i < 4; i++) {
            ah[i] = *(const bf16x8*)(&sAh[(wr + i * 16 + l15) * 32 + quad * 8]);
            al[i] = *(const bf16x8*)(&sAl[(wr + i * 16 + l15) * 32 + quad * 8]);
        }
#pragma unroll
        for (int j = 0; j < 4; j++) {
            bh[j] = *(const bf16x8*)(&sBh[(wc + j * 16 + l15) * 32 + quad * 8]);
            bl[j] = *(const bf16x8*)(&sBl[(wc + j * 16 + l15) * 32 + quad * 8]);
        }
#pragma unroll
        for (int i = 0; i < 4; i++)
#pragma unroll
            for (int j = 0; j < 4; j++) {
                acc[i][j] = __builtin_amdgcn_mfma_f32_16x16x32_bf16(ah[i], bh[j], acc[i][j], 0, 0, 0);
                acc[i][j] = __builtin_amdgcn_mfma_f32_16x16x32_bf16(ah[i], bl[j], acc[i][j], 0, 0, 0);
                acc[i][j] = __builtin_amdgcn_mfma_f32_16x16x32_bf16(al[i], bh[j], acc[i][j], 0, 0, 0);
            }
        __syncthreads();
    }

#pragma unroll
    for (int i = 0; i < 4; i++) {
        int row_base = m0 + wr + i * 16 + quad * 4;
#pragma unroll
        for (int j = 0; j < 4; j++) {
            int col = n0 + wc + j * 16 + l15;
#pragma unroll
            for (int r = 0; r < 4; r++)
                C[(int64_t)(row_base + r) * N + col] = acc[i][j][r];
        }
    }
}

// --------------------------- column softmax --------------------------------
// stats over axis t (column-wise). Stage 1: per-(chunk of 128 t) online m/sum.
__global__ void k_colstats1(const float* __restrict__ L,
                            float* __restrict__ pm, float* __restrict__ ps)
{
    int b = blockIdx.z;                       // 4
    int chunk = blockIdx.y;                   // 16
    int s = blockIdx.x * 256 + threadIdx.x;   // 2048
    const float* col = L + ((int64_t)b * S_ + chunk * 128) * S_ + s;
    float m = -3.0e38f, sum = 0.f;
#pragma unroll 4
    for (int tt = 0; tt < 128; tt++) {
        float x  = col[(int64_t)tt * S_];
        float nm = fmaxf(m, x);
        sum = sum * __expf(m - nm) + __expf(x - nm);
        m = nm;
    }
    int idx = chunk * (B_ * S_) + b * S_ + s;
    pm[idx] = m;
    ps[idx] = sum;
}

__global__ void k_colstats2(const float* __restrict__ pm, const float* __restrict__ ps,
                            float* __restrict__ cmax, float* __restrict__ cinv)
{
    int i = blockIdx.x * 256 + threadIdx.x;   // 8192
    float m = -3.0e38f;
#pragma unroll
    for (int c = 0; c < 16; c++) m = fmaxf(m, pm[c * (B_ * S_) + i]);
    float sum = 0.f;
#pragma unroll
    for (int c = 0; c < 16; c++) sum += ps[c * (B_ * S_) + i] * __expf(pm[c * (B_ * S_) + i] - m);
    cmax[i] = m;
    cinv[i] = 1.0f / sum;
}

// weight = exp(L - cmax)/csum, in place; also emit bf16 copy for GEMM2
__global__ void k_softmax_norm(float* __restrict__ L, const float* __restrict__ cmax,
                               const float* __restrict__ cinv, ushort_t* __restrict__ wbf)
{
    const int64_t n = (int64_t)B_ * S_ * S_;
    for (int64_t i = (int64_t)blockIdx.x * blockDim.x + threadIdx.x; i < n;
         i += (int64_t)gridDim.x * blockDim.x) {
        int b  = (int)(i >> 22);              // S_*S_ = 2^22
        int s  = (int)(i & (S_ - 1));
        int st = (b << 11) + s;
        float w = __expf(L[i] - cmax[st]) * cinv[st];
        L[i]   = w;
        wbf[i] = f2bf(w);
    }
}

// ------------------------------- GEMM 2 ------------------------------------
// weight_sum[b] = weight[b] (2048x2048) @ src[b] -> NT with srcT [d, s]
// epilogue writes bf16 into A_cat[:, 0:1024]
__launch_bounds__(256)
__global__ void k_gemm_wsum(const ushort_t* __restrict__ Wt, const ushort_t* __restrict__ Bt,
                            ushort_t* __restrict__ acat)
{
    const int M = S_, N = D_, K = S_;
    int b = blockIdx.z;
    const ushort_t* A  = Wt + (int64_t)b * M * K;
    const ushort_t* Bm = Bt + (int64_t)b * N * K;

    __shared__ __align__(16) ushort_t sA[128 * 32], sB[128 * 32];

    int t    = threadIdx.x;
    int m0   = blockIdx.y * 128, n0 = blockIdx.x * 128;
    int wave = t >> 6, lane = t & 63;
    int wr   = (wave >> 1) * 64, wc = (wave & 1) * 64;
    int l15  = lane & 15, quad = lane >> 4;

    f32x4 acc[4][4];
#pragma unroll
    for (int i = 0; i < 4; i++)
#pragma unroll
        for (int j = 0; j < 4; j++) acc[i][j] = (f32x4){0.f, 0.f, 0.f, 0.f};

    int srow = t >> 2, scol = (t & 3) * 8;

    for (int k0 = 0; k0 < K; k0 += 32) {
        *(uint4*)(&sA[srow * 32 + scol])        = *(const uint4*)(A  + (int64_t)(m0 + srow) * K + k0 + scol);
        *(uint4*)(&sA[(srow + 64) * 32 + scol]) = *(const uint4*)(A  + (int64_t)(m0 + srow + 64) * K + k0 + scol);
        *(uint4*)(&sB[srow * 32 + scol])        = *(const uint4*)(Bm + (int64_t)(n0 + srow) * K + k0 + scol);
        *(uint4*)(&sB[(srow + 64) * 32 + scol]) = *(const uint4*)(Bm + (int64_t)(n0 + srow + 64) * K + k0 + scol);
        __syncthreads();

        bf16x8 af[4], bf[4];
#pragma unroll
        for (int i = 0; i < 4; i++) af[i] = *(const bf16x8*)(&sA[(wr + i * 16 + l15) * 32 + quad * 8]);
#pragma unroll
        for (int j = 0; j < 4; j++) bf[j] = *(const bf16x8*)(&sB[(wc + j * 16 + l15) * 32 + quad * 8]);
#pragma unroll
        for (int i = 0; i < 4; i++)
#pragma unroll
            for (int j = 0; j < 4; j++)
                acc[i][j] = __builtin_amdgcn_mfma_f32_16x16x32_bf16(af[i], bf[j], acc[i][j], 0, 0, 0);
        __syncthreads();
    }

#pragma unroll
    for (int i = 0; i < 4; i++) {
        int row_base = m0 + wr + i * 16 + quad * 4;
#pragma unroll
        for (int j = 0; j < 4; j++) {
            int col = n0 + wc + j * 16 + l15;
#pragma unroll
            for (int r = 0; r < 4; r++)
                acat[((int64_t)b * S_ + row_base + r) * K2 + col] = f2bf(acc[i][j][r]);
        }
    }
}

// ------------------------------- GEMM 3 ------------------------------------
// out = A_cat (8192x2048) @ W^T + bias   (NT, W row-major [1024, 2048])
__launch_bounds__(256)
__global__ void k_gemm_out(const ushort_t* __restrict__ A, const ushort_t* __restrict__ Bw,
                           const float* __restrict__ bias, float* __restrict__ out)
{
    const int N = OUTD, K = K2;

    __shared__ __align__(16) ushort_t sA[128 * 32], sB[128 * 32];

    int t    = threadIdx.x;
    int m0   = blockIdx.y * 128, n0 = blockIdx.x * 128;
    int wave = t >> 6, lane = t & 63;
    int wr   = (wave >> 1) * 64, wc = (wave & 1) * 64;
    int l15  = lane & 15, quad = lane >> 4;

    f32x4 acc[4][4];
#pragma unroll
    for (int i = 0; i < 4; i++)
#pragma unroll
        for (int j = 0; j < 4; j++) acc[i][j] = (f32x4){0.f, 0.f, 0.f, 0.f};

    int srow = t >> 2, scol = (t & 3) * 8;

    for (int k0 = 0; k0 < K; k0 += 32) {
        *(uint4*)(&sA[srow * 32 + scol])        = *(const uint4*)(A  + (int64_t)(m0 + srow) * K + k0 + scol);
        *(uint4*)(&sA[(srow + 64) * 32 + scol]) = *(const uint4*)(A  + (int64_t)(m0 + srow + 64) * K + k0 + scol);
        *(uint4*)(&sB[srow * 32 + scol])        = *(const uint4*)(Bw + (int64_t)(n0 + srow) * K + k0 + scol);
        *(uint4*)(&sB[(srow + 64) * 32 + scol]) = *(const uint4*)(Bw + (int64_t)(n0 + srow + 64) * K + k0 + scol);
        __syncthreads();

        bf16x8 af[4], bf[4];
#pragma unroll
        for (int i = 0; i < 4; i++) af[i] = *(const bf16x8*)(&sA[(wr + i * 16 + l15) * 32 + quad * 8]);
#pragma unroll
        for (int j = 0; j < 4; j++) bf[j] = *(const bf16x8*)(&sB[(wc + j * 16 + l15) * 32 + quad * 8]);
#pragma unroll
        for (int i = 0; i < 4; i++)
#pragma unroll
            for (int j = 0; j < 4; j++)
                acc[i][j] = __builtin_amdgcn_mfma_f32_16x16x32_bf16(af[i], bf[j], acc[i][j], 0, 0, 0);
        __syncthreads();
    }

#pragma unroll
    for (int i = 0; i < 4; i++) {
        int row_base = m0 + wr + i * 16 + quad * 4;
#pragma unroll
        for (int j = 0; j < 4; j++) {
            int col = n0 + wc + j * 16 + l15;
            float bv = bias[col];
#pragma unroll
            for (int r = 0; r < 4; r++)
                out[(int64_t)(row_base + r) * N + col] = acc[i][j][r] + bv;
        }
    }
}

// ------------------------------- launcher ----------------------------------

extern "C" void kernel_launch(void* const* d_in, const int* in_sizes, int n_in,
                              void* d_out, int out_size, void* d_ws, size_t ws_size,
                              hipStream_t stream)
{
    const float* src  = (const float*)d_in[0];
    const float* tgt  = (const float*)d_in[1];
    const float* W    = (const float*)d_in[2];
    const float* bias = (const float*)d_in[3];

    float* out = (float*)d_out;                           // [4,2048,1024]
    float* Lw  = out + (size_t)B_ * S_ * OUTD;            // [4,2048,2048] logits -> weight

    char*  ws = (char*)d_ws;
    size_t o  = 0;
    auto take = [&](size_t bytes) -> char* {
        char* p = ws + o;
        o += (bytes + 255) & ~(size_t)255;
        return p;
    };
    const size_t ELEMS = (size_t)B_ * S_ * D_;            // 8,388,608
    ushort_t* sh   = (ushort_t*)take(ELEMS * 2);          // src hi
    ushort_t* sl   = (ushort_t*)take(ELEMS * 2);          // src lo
    ushort_t* th   = (ushort_t*)take(ELEMS * 2);          // tgt hi
    ushort_t* tl   = (ushort_t*)take(ELEMS * 2);          // tgt lo
    ushort_t* sT   = (ushort_t*)take(ELEMS * 2);          // srcT bf16 [b,d,s]
    ushort_t* wbf  = (ushort_t*)take((size_t)B_ * S_ * S_ * 2);   // weight bf16
    ushort_t* acat = (ushort_t*)take((size_t)B_ * S_ * K2 * 2);   // [ws | tgt] bf16
    ushort_t* wb   = (ushort_t*)take((size_t)OUTD * K2 * 2);      // W bf16
    float*    pm   = (float*)take(16 * (size_t)B_ * S_ * 4);
    float*    ps   = (float*)take(16 * (size_t)B_ * S_ * 4);
    float*    cmax = (float*)take((size_t)B_ * S_ * 4);
    float*    cinv = (float*)take((size_t)B_ * S_ * 4);
    (void)ws_size; (void)in_sizes; (void)n_in; (void)out_size;

    k_split<<<dim3(4096), dim3(256), 0, stream>>>(src, tgt, sh, sl, th, tl, acat);
    k_wconv<<<dim3(1024), dim3(256), 0, stream>>>(W, wb);
    k_transpose<<<dim3(32, 64, 4), dim3(32, 8), 0, stream>>>(src, sT);

    k_gemm_logits<<<dim3(16, 16, 4), dim3(256), 0, stream>>>(th, tl, sh, sl, Lw);

    k_colstats1<<<dim3(8, 16, 4), dim3(256), 0, stream>>>(Lw, pm, ps);
    k_colstats2<<<dim3(32), dim3(256), 0, stream>>>(pm, ps, cmax, cinv);
    k_softmax_norm<<<dim3(4096), dim3(256), 0, stream>>>(Lw, cmax, cinv, wbf);

    k_gemm_wsum<<<dim3(8, 16, 4), dim3(256), 0, stream>>>(wbf, sT, acat);
    k_gemm_out<<<dim3(8, 64), dim3(256), 0, stream>>>(acat, wb, bias, out);
}

// Round 2
// 419.902 us; speedup vs baseline: 1.0488x; 1.0488x over previous
//
#include <hip/hip_runtime.h>
#include <stdint.h>

// ---------------------------------------------------------------------------
// Attention_18116172054662 on MI355X (gfx950)
//   L = tgt @ src^T  (split-bf16 triple MFMA for f32-grade logits)
//   weight = softmax(L, axis=tgt)   -> second output (f32, in place in d_out)
//   weight_sum = weight @ src       (bf16 MFMA, NT via pre-transposed src)
//   out = [weight_sum | tgt] @ W^T + b   (bf16 MFMA NT)
// R1: global_load_lds width-16 staging in all GEMMs (m97 structure),
//     column-stats fused into gemm_logits epilogue, vectorized elementwise.
// ---------------------------------------------------------------------------

#define B_   4
#define S_   2048
#define D_   1024
#define OUTD 1024
#define K2   2048   // 2*D

typedef unsigned short ushort_t;
typedef __bf16 bf16x8 __attribute__((ext_vector_type(8)));
typedef float  f32x4  __attribute__((ext_vector_type(4)));

__device__ __forceinline__ ushort_t f2bf(float f) {
    uint32_t u = __float_as_uint(f);
    uint32_t r = (u + 0x7FFFu + ((u >> 16) & 1u)) >> 16;   // RNE
    return (ushort_t)r;
}
__device__ __forceinline__ float bf2f(ushort_t h) {
    return __uint_as_float(((uint32_t)h) << 16);
}

// async global->LDS, 16B per lane; LDS dest = wave-uniform base + lane*16
__device__ __forceinline__ void ld16(const ushort_t* g, ushort_t* l) {
    __builtin_amdgcn_global_load_lds(
        (const __attribute__((address_space(1))) void*)g,
        (__attribute__((address_space(3))) void*)l, 16, 0, 0);
}

// --------------------------- elementwise prep ------------------------------

// split src/tgt into bf16 hi/lo; also drop tgt_hi into A_cat[:,1024:2048]
__global__ void k_split(const float4* __restrict__ src, const float4* __restrict__ tgt,
                        ushort4* __restrict__ sh, ushort4* __restrict__ sl,
                        ushort4* __restrict__ th, ushort4* __restrict__ tl,
                        ushort4* __restrict__ acat)
{
    const int64_t n4 = (int64_t)B_ * S_ * D_ / 4;
    for (int64_t i = (int64_t)blockIdx.x * blockDim.x + threadIdx.x; i < n4;
         i += (int64_t)gridDim.x * blockDim.x) {
        float4 s = src[i];
        ushort4 hs = {f2bf(s.x), f2bf(s.y), f2bf(s.z), f2bf(s.w)};
        sh[i] = hs;
        ushort4 ls = {f2bf(s.x - bf2f(hs.x)), f2bf(s.y - bf2f(hs.y)),
                      f2bf(s.z - bf2f(hs.z)), f2bf(s.w - bf2f(hs.w))};
        sl[i] = ls;
        float4 tv = tgt[i];
        ushort4 ht = {f2bf(tv.x), f2bf(tv.y), f2bf(tv.z), f2bf(tv.w)};
        th[i] = ht;
        ushort4 lt = {f2bf(tv.x - bf2f(ht.x)), f2bf(tv.y - bf2f(ht.y)),
                      f2bf(tv.z - bf2f(ht.z)), f2bf(tv.w - bf2f(ht.w))};
        tl[i] = lt;
        int64_t row = i >> 8;                 // 256 float4 per D_ row
        acat[row * 512 + 256 + (i & 255)] = ht;
    }
}

__global__ void k_wconv(const float4* __restrict__ W, ushort4* __restrict__ wb)
{
    const int64_t n4 = (int64_t)OUTD * K2 / 4;
    for (int64_t i = (int64_t)blockIdx.x * blockDim.x + threadIdx.x; i < n4;
         i += (int64_t)gridDim.x * blockDim.x) {
        float4 w = W[i];
        wb[i] = (ushort4){f2bf(w.x), f2bf(w.y), f2bf(w.z), f2bf(w.w)};
    }
}

// srcT[b,d,s] = bf16(src[b,s,d])  (for the NT form of GEMM2)
__global__ void k_transpose(const float* __restrict__ src, ushort_t* __restrict__ sT)
{
    __shared__ ushort_t tile[32][33];
    int b  = blockIdx.z;
    int d0 = blockIdx.x * 32, s0 = blockIdx.y * 32;
    int tx = threadIdx.x, ty = threadIdx.y;   // block (32,8)
#pragma unroll
    for (int i = 0; i < 4; i++) {
        int s = s0 + ty + i * 8;
        tile[ty + i * 8][tx] = f2bf(src[((int64_t)b * S_ + s) * D_ + d0 + tx]);
    }
    __syncthreads();
#pragma unroll
    for (int i = 0; i < 4; i++) {
        int d = d0 + ty + i * 8;
        sT[((int64_t)b * D_ + d) * S_ + s0 + tx] = tile[tx][ty + i * 8];
    }
}

// ------------------------------- GEMM 1 ------------------------------------
// L[b] = tgt[b] @ src[b]^T with split-bf16:  Ah*Bh + Ah*Bl + Al*Bh
// 128x128 tile, BK=32, 256 threads = 4 waves in 2x2, 16x16x32 bf16 MFMA.
// Epilogue: per-block (128-row chunk) column max/sumexp -> pm/ps.
__launch_bounds__(256)
__global__ void k_gemm_logits(const ushort_t* __restrict__ Ah, const ushort_t* __restrict__ Al,
                              const ushort_t* __restrict__ Bh, const ushort_t* __restrict__ Bl,
                              float* __restrict__ C,
                              float* __restrict__ pm, float* __restrict__ ps)
{
    const int M = S_, N = S_, K = D_;
    int b = blockIdx.z;
    Ah += (int64_t)b * M * K;  Al += (int64_t)b * M * K;
    Bh += (int64_t)b * N * K;  Bl += (int64_t)b * N * K;
    C  += (int64_t)b * M * N;

    __shared__ __align__(16) ushort_t sAh[128 * 32], sAl[128 * 32];
    __shared__ __align__(16) ushort_t sBh[128 * 32], sBl[128 * 32];
    __shared__ float red_m[2][128], red_s[2][128];

    int t    = threadIdx.x;
    int m0   = blockIdx.y * 128, n0 = blockIdx.x * 128;
    int wave = t >> 6, lane = t & 63;
    int wr   = (wave >> 1) * 64, wc = (wave & 1) * 64;
    int l15  = lane & 15, quad = lane >> 4;

    f32x4 acc[4][4];
#pragma unroll
    for (int i = 0; i < 4; i++)
#pragma unroll
        for (int j = 0; j < 4; j++) acc[i][j] = (f32x4){0.f, 0.f, 0.f, 0.f};

    int srow = t >> 2;          // 0..63
    int scol = (t & 3) * 8;     // 0/8/16/24 (bf16)

    const ushort_t* gAh0 = Ah + (int64_t)(m0 + srow) * K + scol;
    const ushort_t* gAh1 = gAh0 + (int64_t)64 * K;
    const ushort_t* gAl0 = Al + (int64_t)(m0 + srow) * K + scol;
    const ushort_t* gAl1 = gAl0 + (int64_t)64 * K;
    const ushort_t* gBh0 = Bh + (int64_t)(n0 + srow) * K + scol;
    const ushort_t* gBh1 = gBh0 + (int64_t)64 * K;
    const ushort_t* gBl0 = Bl + (int64_t)(n0 + srow) * K + scol;
    const ushort_t* gBl1 = gBl0 + (int64_t)64 * K;

    ushort_t* lAh0 = sAh + wave * 512;  ushort_t* lAh1 = sAh + 2048 + wave * 512;
    ushort_t* lAl0 = sAl + wave * 512;  ushort_t* lAl1 = sAl + 2048 + wave * 512;
    ushort_t* lBh0 = sBh + wave * 512;  ushort_t* lBh1 = sBh + 2048 + wave * 512;
    ushort_t* lBl0 = sBl + wave * 512;  ushort_t* lBl1 = sBl + 2048 + wave * 512;

    for (int k0 = 0; k0 < K; k0 += 32) {
        ld16(gAh0, lAh0);  ld16(gAh1, lAh1);
        ld16(gAl0, lAl0);  ld16(gAl1, lAl1);
        ld16(gBh0, lBh0);  ld16(gBh1, lBh1);
        ld16(gBl0, lBl0);  ld16(gBl1, lBl1);
        gAh0 += 32; gAh1 += 32; gAl0 += 32; gAl1 += 32;
        gBh0 += 32; gBh1 += 32; gBl0 += 32; gBl1 += 32;
        __syncthreads();

        bf16x8 ah[4], al[4], bh[4], bl[4];
#pragma unroll
        for (int i = 0; i < 4; i++) {
            ah[i] = *(const bf16x8*)(&sAh[(wr + i * 16 + l15) * 32 + quad * 8]);
            al[i] = *(const bf16x8*)(&sAl[(wr + i * 16 + l15) * 32 + quad * 8]);
        }
#pragma unroll
        for (int j = 0; j < 4; j++) {
            bh[j] = *(const bf16x8*)(&sBh[(wc + j * 16 + l15) * 32 + quad * 8]);
            bl[j] = *(const bf16x8*)(&sBl[(wc + j * 16 + l15) * 32 + quad * 8]);
        }
#pragma unroll
        for (int i = 0; i < 4; i++)
#pragma unroll
            for (int j = 0; j < 4; j++) {
                acc[i][j] = __builtin_amdgcn_mfma_f32_16x16x32_bf16(ah[i], bh[j], acc[i][j], 0, 0, 0);
                acc[i][j] = __builtin_amdgcn_mfma_f32_16x16x32_bf16(ah[i], bl[j], acc[i][j], 0, 0, 0);
                acc[i][j] = __builtin_amdgcn_mfma_f32_16x16x32_bf16(al[i], bh[j], acc[i][j], 0, 0, 0);
            }
        __syncthreads();
    }

    // C store
#pragma unroll
    for (int i = 0; i < 4; i++) {
        int row_base = m0 + wr + i * 16 + quad * 4;
#pragma unroll
        for (int j = 0; j < 4; j++) {
            int col = n0 + wc + j * 16 + l15;
#pragma unroll
            for (int r = 0; r < 4; r++)
                C[(int64_t)(row_base + r) * N + col] = acc[i][j][r];
        }
    }

    // fused partial column stats (max & sumexp over this block's 128 rows)
    int rowhalf = wave >> 1;
#pragma unroll
    for (int j = 0; j < 4; j++) {
        float m = -3.0e38f;
#pragma unroll
        for (int i = 0; i < 4; i++)
#pragma unroll
            for (int r = 0; r < 4; r++) m = fmaxf(m, acc[i][j][r]);
        float s = 0.f;
#pragma unroll
        for (int i = 0; i < 4; i++)
#pragma unroll
            for (int r = 0; r < 4; r++) s += __expf(acc[i][j][r] - m);
        // reduce across the 4 quads (lanes l15, l15+16, l15+32, l15+48)
#pragma unroll
        for (int d = 16; d <= 32; d <<= 1) {
            float m2 = __shfl_xor(m, d, 64);
            float s2 = __shfl_xor(s, d, 64);
            float nm = fmaxf(m, m2);
            s = s * __expf(m - nm) + s2 * __expf(m2 - nm);
            m = nm;
        }
        if (lane < 16) {
            red_m[rowhalf][wc + j * 16 + l15] = m;
            red_s[rowhalf][wc + j * 16 + l15] = s;
        }
    }
    __syncthreads();
    if (t < 128) {
        float ma = red_m[0][t], mb = red_m[1][t];
        float sa = red_s[0][t], sb = red_s[1][t];
        float m = fmaxf(ma, mb);
        float s = sa * __expf(ma - m) + sb * __expf(mb - m);
        int idx = blockIdx.y * (B_ * S_) + b * S_ + n0 + t;
        pm[idx] = m;
        ps[idx] = s;
    }
}

// --------------------------- column softmax --------------------------------

__global__ void k_colstats2(const float* __restrict__ pm, const float* __restrict__ ps,
                            float* __restrict__ cmax, float* __restrict__ cinv)
{
    int i = blockIdx.x * 256 + threadIdx.x;   // 8192
    float m = -3.0e38f;
#pragma unroll
    for (int c = 0; c < 16; c++) m = fmaxf(m, pm[c * (B_ * S_) + i]);
    float sum = 0.f;
#pragma unroll
    for (int c = 0; c < 16; c++) sum += ps[c * (B_ * S_) + i] * __expf(pm[c * (B_ * S_) + i] - m);
    cmax[i] = m;
    cinv[i] = 1.0f / sum;
}

// weight = exp(L - cmax)/csum, in place; also emit bf16 copy for GEMM2
__global__ void k_softmax_norm(float4* __restrict__ L, const float4* __restrict__ cmax4,
                               const float4* __restrict__ cinv4, ushort4* __restrict__ wbf)
{
    const int64_t n4 = (int64_t)B_ * S_ * S_ / 4;
    for (int64_t i = (int64_t)blockIdx.x * blockDim.x + threadIdx.x; i < n4;
         i += (int64_t)gridDim.x * blockDim.x) {
        int b  = (int)(i >> 20);              // S_*S_/4 = 2^20 float4 per batch
        int c4 = (int)(i & 511);              // (element s)/4
        float4 x  = L[i];
        float4 cm = cmax4[b * 512 + c4];
        float4 ci = cinv4[b * 512 + c4];
        float4 w;
        w.x = __expf(x.x - cm.x) * ci.x;
        w.y = __expf(x.y - cm.y) * ci.y;
        w.z = __expf(x.z - cm.z) * ci.z;
        w.w = __expf(x.w - cm.w) * ci.w;
        L[i] = w;
        wbf[i] = (ushort4){f2bf(w.x), f2bf(w.y), f2bf(w.z), f2bf(w.w)};
    }
}

// ------------------------------- GEMM 2 ------------------------------------
// weight_sum[b] = weight[b] (2048x2048) @ src[b] -> NT with srcT [d, s]
// epilogue writes bf16 into A_cat[:, 0:1024]
__launch_bounds__(256)
__global__ void k_gemm_wsum(const ushort_t* __restrict__ Wt, const ushort_t* __restrict__ Bt,
                            ushort_t* __restrict__ acat)
{
    const int M = S_, N = D_, K = S_;
    int b = blockIdx.z;
    const ushort_t* A  = Wt + (int64_t)b * M * K;
    const ushort_t* Bm = Bt + (int64_t)b * N * K;

    __shared__ __align__(16) ushort_t sA[128 * 32], sB[128 * 32];

    int t    = threadIdx.x;
    int m0   = blockIdx.y * 128, n0 = blockIdx.x * 128;
    int wave = t >> 6, lane = t & 63;
    int wr   = (wave >> 1) * 64, wc = (wave & 1) * 64;
    int l15  = lane & 15, quad = lane >> 4;

    f32x4 acc[4][4];
#pragma unroll
    for (int i = 0; i < 4; i++)
#pragma unroll
        for (int j = 0; j < 4; j++) acc[i][j] = (f32x4){0.f, 0.f, 0.f, 0.f};

    int srow = t >> 2, scol = (t & 3) * 8;

    const ushort_t* gA0 = A  + (int64_t)(m0 + srow) * K + scol;
    const ushort_t* gA1 = gA0 + (int64_t)64 * K;
    const ushort_t* gB0 = Bm + (int64_t)(n0 + srow) * K + scol;
    const ushort_t* gB1 = gB0 + (int64_t)64 * K;
    ushort_t* lA0 = sA + wave * 512;  ushort_t* lA1 = sA + 2048 + wave * 512;
    ushort_t* lB0 = sB + wave * 512;  ushort_t* lB1 = sB + 2048 + wave * 512;

    for (int k0 = 0; k0 < K; k0 += 32) {
        ld16(gA0, lA0);  ld16(gA1, lA1);
        ld16(gB0, lB0);  ld16(gB1, lB1);
        gA0 += 32; gA1 += 32; gB0 += 32; gB1 += 32;
        __syncthreads();

        bf16x8 af[4], bf[4];
#pragma unroll
        for (int i = 0; i < 4; i++) af[i] = *(const bf16x8*)(&sA[(wr + i * 16 + l15) * 32 + quad * 8]);
#pragma unroll
        for (int j = 0; j < 4; j++) bf[j] = *(const bf16x8*)(&sB[(wc + j * 16 + l15) * 32 + quad * 8]);
#pragma unroll
        for (int i = 0; i < 4; i++)
#pragma unroll
            for (int j = 0; j < 4; j++)
                acc[i][j] = __builtin_amdgcn_mfma_f32_16x16x32_bf16(af[i], bf[j], acc[i][j], 0, 0, 0);
        __syncthreads();
    }

#pragma unroll
    for (int i = 0; i < 4; i++) {
        int row_base = m0 + wr + i * 16 + quad * 4;
#pragma unroll
        for (int j = 0; j < 4; j++) {
            int col = n0 + wc + j * 16 + l15;
#pragma unroll
            for (int r = 0; r < 4; r++)
                acat[((int64_t)b * S_ + row_base + r) * K2 + col] = f2bf(acc[i][j][r]);
        }
    }
}

// ------------------------------- GEMM 3 ------------------------------------
// out = A_cat (8192x2048) @ W^T + bias   (NT, W row-major [1024, 2048])
__launch_bounds__(256)
__global__ void k_gemm_out(const ushort_t* __restrict__ A, const ushort_t* __restrict__ Bw,
                           const float* __restrict__ bias, float* __restrict__ out)
{
    const int N = OUTD, K = K2;

    __shared__ __align__(16) ushort_t sA[128 * 32], sB[128 * 32];

    int t    = threadIdx.x;
    int m0   = blockIdx.y * 128, n0 = blockIdx.x * 128;
    int wave = t >> 6, lane = t & 63;
    int wr   = (wave >> 1) * 64, wc = (wave & 1) * 64;
    int l15  = lane & 15, quad = lane >> 4;

    f32x4 acc[4][4];
#pragma unroll
    for (int i = 0; i < 4; i++)
#pragma unroll
        for (int j = 0; j < 4; j++) acc[i][j] = (f32x4){0.f, 0.f, 0.f, 0.f};

    int srow = t >> 2, scol = (t & 3) * 8;

    const ushort_t* gA0 = A  + (int64_t)(m0 + srow) * K + scol;
    const ushort_t* gA1 = gA0 + (int64_t)64 * K;
    const ushort_t* gB0 = Bw + (int64_t)(n0 + srow) * K + scol;
    const ushort_t* gB1 = gB0 + (int64_t)64 * K;
    ushort_t* lA0 = sA + wave * 512;  ushort_t* lA1 = sA + 2048 + wave * 512;
    ushort_t* lB0 = sB + wave * 512;  ushort_t* lB1 = sB + 2048 + wave * 512;

    for (int k0 = 0; k0 < K; k0 += 32) {
        ld16(gA0, lA0);  ld16(gA1, lA1);
        ld16(gB0, lB0);  ld16(gB1, lB1);
        gA0 += 32; gA1 += 32; gB0 += 32; gB1 += 32;
        __syncthreads();

        bf16x8 af[4], bf[4];
#pragma unroll
        for (int i = 0; i < 4; i++) af[i] = *(const bf16x8*)(&sA[(wr + i * 16 + l15) * 32 + quad * 8]);
#pragma unroll
        for (int j = 0; j < 4; j++) bf[j] = *(const bf16x8*)(&sB[(wc + j * 16 + l15) * 32 + quad * 8]);
#pragma unroll
        for (int i = 0; i < 4; i++)
#pragma unroll
            for (int j = 0; j < 4; j++)
                acc[i][j] = __builtin_amdgcn_mfma_f32_16x16x32_bf16(af[i], bf[j], acc[i][j], 0, 0, 0);
        __syncthreads();
    }

#pragma unroll
    for (int i = 0; i < 4; i++) {
        int row_base = m0 + wr + i * 16 + quad * 4;
#pragma unroll
        for (int j = 0; j < 4; j++) {
            int col = n0 + wc + j * 16 + l15;
            float bv = bias[col];
#pragma unroll
            for (int r = 0; r < 4; r++)
                out[(int64_t)(row_base + r) * N + col] = acc[i][j][r] + bv;
        }
    }
}

// ------------------------------- launcher ----------------------------------

extern "C" void kernel_launch(void* const* d_in, const int* in_sizes, int n_in,
                              void* d_out, int out_size, void* d_ws, size_t ws_size,
                              hipStream_t stream)
{
    const float* src  = (const float*)d_in[0];
    const float* tgt  = (const float*)d_in[1];
    const float* W    = (const float*)d_in[2];
    const float* bias = (const float*)d_in[3];

    float* out = (float*)d_out;                           // [4,2048,1024]
    float* Lw  = out + (size_t)B_ * S_ * OUTD;            // [4,2048,2048] logits -> weight

    char*  ws = (char*)d_ws;
    size_t o  = 0;
    auto take = [&](size_t bytes) -> char* {
        char* p = ws + o;
        o += (bytes + 255) & ~(size_t)255;
        return p;
    };
    const size_t ELEMS = (size_t)B_ * S_ * D_;            // 8,388,608
    ushort_t* sh   = (ushort_t*)take(ELEMS * 2);          // src hi
    ushort_t* sl   = (ushort_t*)take(ELEMS * 2);          // src lo
    ushort_t* th   = (ushort_t*)take(ELEMS * 2);          // tgt hi
    ushort_t* tl   = (ushort_t*)take(ELEMS * 2);          // tgt lo
    ushort_t* sT   = (ushort_t*)take(ELEMS * 2);          // srcT bf16 [b,d,s]
    ushort_t* wbf  = (ushort_t*)take((size_t)B_ * S_ * S_ * 2);   // weight bf16
    ushort_t* acat = (ushort_t*)take((size_t)B_ * S_ * K2 * 2);   // [ws | tgt] bf16
    ushort_t* wb   = (ushort_t*)take((size_t)OUTD * K2 * 2);      // W bf16
    float*    pm   = (float*)take(16 * (size_t)B_ * S_ * 4);
    float*    ps   = (float*)take(16 * (size_t)B_ * S_ * 4);
    float*    cmax = (float*)take((size_t)B_ * S_ * 4);
    float*    cinv = (float*)take((size_t)B_ * S_ * 4);
    (void)ws_size; (void)in_sizes; (void)n_in; (void)out_size;

    k_split<<<dim3(2048), dim3(256), 0, stream>>>((const float4*)src, (const float4*)tgt,
                                                  (ushort4*)sh, (ushort4*)sl,
                                                  (ushort4*)th, (ushort4*)tl, (ushort4*)acat);
    k_wconv<<<dim3(512), dim3(256), 0, stream>>>((const float4*)W, (ushort4*)wb);
    k_transpose<<<dim3(32, 64, 4), dim3(32, 8), 0, stream>>>(src, sT);

    k_gemm_logits<<<dim3(16, 16, 4), dim3(256), 0, stream>>>(th, tl, sh, sl, Lw, pm, ps);

    k_colstats2<<<dim3(32), dim3(256), 0, stream>>>(pm, ps, cmax, cinv);
    k_softmax_norm<<<dim3(2048), dim3(256), 0, stream>>>((float4*)Lw, (const float4*)cmax,
                                                         (const float4*)cinv, (ushort4*)wbf);

    k_gemm_wsum<<<dim3(8, 16, 4), dim3(256), 0, stream>>>(wbf, sT, acat);
    k_gemm_out<<<dim3(8, 64), dim3(256), 0, stream>>>(acat, wb, bias, out);
}

// Round 3
// 415.211 us; speedup vs baseline: 1.0607x; 1.0113x over previous
//
#include <hip/hip_runtime.h>
#include <stdint.h>

// ---------------------------------------------------------------------------
// Attention_18116172054662 on MI355X (gfx950)
//   L = tgt @ src^T  (split-bf16 triple MFMA for f32-grade logits)
//   weight = softmax(L, axis=tgt)   -> second output (f32, in place in d_out)
//   weight_sum = weight @ src       (bf16 MFMA, NT via pre-transposed src)
//   out = [weight_sum | tgt] @ W^T + b   (bf16 MFMA NT)
// R1: global_load_lds width-16 staging, fused column stats, vectorized EW.
// R2: XOR-swizzled LDS layout (slot = chunk ^ ((row>>1)&3)) in all GEMMs to
//     kill the measured 4-cyc/ds_read bank conflicts (8.4M = 4/read on R1).
// ---------------------------------------------------------------------------

#define B_   4
#define S_   2048
#define D_   1024
#define OUTD 1024
#define K2   2048   // 2*D

typedef unsigned short ushort_t;
typedef __bf16 bf16x8 __attribute__((ext_vector_type(8)));
typedef float  f32x4  __attribute__((ext_vector_type(4)));

__device__ __forceinline__ ushort_t f2bf(float f) {
    uint32_t u = __float_as_uint(f);
    uint32_t r = (u + 0x7FFFu + ((u >> 16) & 1u)) >> 16;   // RNE
    return (ushort_t)r;
}
__device__ __forceinline__ float bf2f(ushort_t h) {
    return __uint_as_float(((uint32_t)h) << 16);
}

// async global->LDS, 16B per lane; LDS dest = wave-uniform base + lane*16
__device__ __forceinline__ void ld16(const ushort_t* g, ushort_t* l) {
    __builtin_amdgcn_global_load_lds(
        (const __attribute__((address_space(1))) void*)g,
        (__attribute__((address_space(3))) void*)l, 16, 0, 0);
}

// --------------------------- elementwise prep ------------------------------

// split src/tgt into bf16 hi/lo; also drop tgt_hi into A_cat[:,1024:2048]
__global__ void k_split(const float4* __restrict__ src, const float4* __restrict__ tgt,
                        ushort4* __restrict__ sh, ushort4* __restrict__ sl,
                        ushort4* __restrict__ th, ushort4* __restrict__ tl,
                        ushort4* __restrict__ acat)
{
    const int64_t n4 = (int64_t)B_ * S_ * D_ / 4;
    for (int64_t i = (int64_t)blockIdx.x * blockDim.x + threadIdx.x; i < n4;
         i += (int64_t)gridDim.x * blockDim.x) {
        float4 s = src[i];
        ushort4 hs = {f2bf(s.x), f2bf(s.y), f2bf(s.z), f2bf(s.w)};
        sh[i] = hs;
        ushort4 ls = {f2bf(s.x - bf2f(hs.x)), f2bf(s.y - bf2f(hs.y)),
                      f2bf(s.z - bf2f(hs.z)), f2bf(s.w - bf2f(hs.w))};
        sl[i] = ls;
        float4 tv = tgt[i];
        ushort4 ht = {f2bf(tv.x), f2bf(tv.y), f2bf(tv.z), f2bf(tv.w)};
        th[i] = ht;
        ushort4 lt = {f2bf(tv.x - bf2f(ht.x)), f2bf(tv.y - bf2f(ht.y)),
                      f2bf(tv.z - bf2f(ht.z)), f2bf(tv.w - bf2f(ht.w))};
        tl[i] = lt;
        int64_t row = i >> 8;                 // 256 float4 per D_ row
        acat[row * 512 + 256 + (i & 255)] = ht;
    }
}

__global__ void k_wconv(const float4* __restrict__ W, ushort4* __restrict__ wb)
{
    const int64_t n4 = (int64_t)OUTD * K2 / 4;
    for (int64_t i = (int64_t)blockIdx.x * blockDim.x + threadIdx.x; i < n4;
         i += (int64_t)gridDim.x * blockDim.x) {
        float4 w = W[i];
        wb[i] = (ushort4){f2bf(w.x), f2bf(w.y), f2bf(w.z), f2bf(w.w)};
    }
}

// srcT[b,d,s] = bf16(src[b,s,d])  (for the NT form of GEMM2)
__global__ void k_transpose(const float* __restrict__ src, ushort_t* __restrict__ sT)
{
    __shared__ ushort_t tile[32][33];
    int b  = blockIdx.z;
    int d0 = blockIdx.x * 32, s0 = blockIdx.y * 32;
    int tx = threadIdx.x, ty = threadIdx.y;   // block (32,8)
#pragma unroll
    for (int i = 0; i < 4; i++) {
        int s = s0 + ty + i * 8;
        tile[ty + i * 8][tx] = f2bf(src[((int64_t)b * S_ + s) * D_ + d0 + tx]);
    }
    __syncthreads();
#pragma unroll
    for (int i = 0; i < 4; i++) {
        int d = d0 + ty + i * 8;
        sT[((int64_t)b * D_ + d) * S_ + s0 + tx] = tile[tx][ty + i * 8];
    }
}

// ------------------------------- GEMM 1 ------------------------------------
// L[b] = tgt[b] @ src[b]^T with split-bf16:  Ah*Bh + Ah*Bl + Al*Bh
// 128x128 tile, BK=32, 256 threads = 4 waves in 2x2, 16x16x32 bf16 MFMA.
// LDS layout XOR-swizzled: slot(row, chunk) = chunk ^ ((row>>1)&3).
// Epilogue: per-block (128-row chunk) column max/sumexp -> pm/ps.
__launch_bounds__(256)
__global__ void k_gemm_logits(const ushort_t* __restrict__ Ah, const ushort_t* __restrict__ Al,
                              const ushort_t* __restrict__ Bh, const ushort_t* __restrict__ Bl,
                              float* __restrict__ C,
                              float* __restrict__ pm, float* __restrict__ ps)
{
    const int M = S_, N = S_, K = D_;
    int b = blockIdx.z;
    Ah += (int64_t)b * M * K;  Al += (int64_t)b * M * K;
    Bh += (int64_t)b * N * K;  Bl += (int64_t)b * N * K;
    C  += (int64_t)b * M * N;

    __shared__ __align__(16) ushort_t sAh[128 * 32], sAl[128 * 32];
    __shared__ __align__(16) ushort_t sBh[128 * 32], sBl[128 * 32];
    __shared__ float red_m[2][128], red_s[2][128];

    int t    = threadIdx.x;
    int m0   = blockIdx.y * 128, n0 = blockIdx.x * 128;
    int wave = t >> 6, lane = t & 63;
    int wr   = (wave >> 1) * 64, wc = (wave & 1) * 64;
    int l15  = lane & 15, quad = lane >> 4;

    f32x4 acc[4][4];
#pragma unroll
    for (int i = 0; i < 4; i++)
#pragma unroll
        for (int j = 0; j < 4; j++) acc[i][j] = (f32x4){0.f, 0.f, 0.f, 0.f};

    int srow = t >> 2;                               // 0..63
    int scol = (((t & 3) ^ ((t >> 3) & 3)) * 8);     // swizzled source chunk
    int slot8 = (quad ^ ((l15 >> 1) & 3)) * 8;       // swizzled read slot

    const ushort_t* gAh0 = Ah + (int64_t)(m0 + srow) * K + scol;
    const ushort_t* gAh1 = gAh0 + (int64_t)64 * K;
    const ushort_t* gAl0 = Al + (int64_t)(m0 + srow) * K + scol;
    const ushort_t* gAl1 = gAl0 + (int64_t)64 * K;
    const ushort_t* gBh0 = Bh + (int64_t)(n0 + srow) * K + scol;
    const ushort_t* gBh1 = gBh0 + (int64_t)64 * K;
    const ushort_t* gBl0 = Bl + (int64_t)(n0 + srow) * K + scol;
    const ushort_t* gBl1 = gBl0 + (int64_t)64 * K;

    ushort_t* lAh0 = sAh + wave * 512;  ushort_t* lAh1 = sAh + 2048 + wave * 512;
    ushort_t* lAl0 = sAl + wave * 512;  ushort_t* lAl1 = sAl + 2048 + wave * 512;
    ushort_t* lBh0 = sBh + wave * 512;  ushort_t* lBh1 = sBh + 2048 + wave * 512;
    ushort_t* lBl0 = sBl + wave * 512;  ushort_t* lBl1 = sBl + 2048 + wave * 512;

    for (int k0 = 0; k0 < K; k0 += 32) {
        ld16(gAh0, lAh0);  ld16(gAh1, lAh1);
        ld16(gAl0, lAl0);  ld16(gAl1, lAl1);
        ld16(gBh0, lBh0);  ld16(gBh1, lBh1);
        ld16(gBl0, lBl0);  ld16(gBl1, lBl1);
        gAh0 += 32; gAh1 += 32; gAl0 += 32; gAl1 += 32;
        gBh0 += 32; gBh1 += 32; gBl0 += 32; gBl1 += 32;
        __syncthreads();

        bf16x8 ah[4], al[4], bh[4], bl[4];
#pragma unroll
        for (int i = 0; i < 4; i++) {
            ah[i] = *(const bf16x8*)(&sAh[(wr + i * 16 + l15) * 32 + slot8]);
            al[i] = *(const bf16x8*)(&sAl[(wr + i * 16 + l15) * 32 + slot8]);
        }
#pragma unroll
        for (int j = 0; j < 4; j++) {
            bh[j] = *(const bf16x8*)(&sBh[(wc + j * 16 + l15) * 32 + slot8]);
            bl[j] = *(const bf16x8*)(&sBl[(wc + j * 16 + l15) * 32 + slot8]);
        }
#pragma unroll
        for (int i = 0; i < 4; i++)
#pragma unroll
            for (int j = 0; j < 4; j++) {
                acc[i][j] = __builtin_amdgcn_mfma_f32_16x16x32_bf16(ah[i], bh[j], acc[i][j], 0, 0, 0);
                acc[i][j] = __builtin_amdgcn_mfma_f32_16x16x32_bf16(ah[i], bl[j], acc[i][j], 0, 0, 0);
                acc[i][j] = __builtin_amdgcn_mfma_f32_16x16x32_bf16(al[i], bh[j], acc[i][j], 0, 0, 0);
            }
        __syncthreads();
    }

    // C store
#pragma unroll
    for (int i = 0; i < 4; i++) {
        int row_base = m0 + wr + i * 16 + quad * 4;
#pragma unroll
        for (int j = 0; j < 4; j++) {
            int col = n0 + wc + j * 16 + l15;
#pragma unroll
            for (int r = 0; r < 4; r++)
                C[(int64_t)(row_base + r) * N + col] = acc[i][j][r];
        }
    }

    // fused partial column stats (max & sumexp over this block's 128 rows)
    int rowhalf = wave >> 1;
#pragma unroll
    for (int j = 0; j < 4; j++) {
        float m = -3.0e38f;
#pragma unroll
        for (int i = 0; i < 4; i++)
#pragma unroll
            for (int r = 0; r < 4; r++) m = fmaxf(m, acc[i][j][r]);
        float s = 0.f;
#pragma unroll
        for (int i = 0; i < 4; i++)
#pragma unroll
            for (int r = 0; r < 4; r++) s += __expf(acc[i][j][r] - m);
        // reduce across the 4 quads (lanes l15, l15+16, l15+32, l15+48)
#pragma unroll
        for (int d = 16; d <= 32; d <<= 1) {
            float m2 = __shfl_xor(m, d, 64);
            float s2 = __shfl_xor(s, d, 64);
            float nm = fmaxf(m, m2);
            s = s * __expf(m - nm) + s2 * __expf(m2 - nm);
            m = nm;
        }
        if (lane < 16) {
            red_m[rowhalf][wc + j * 16 + l15] = m;
            red_s[rowhalf][wc + j * 16 + l15] = s;
        }
    }
    __syncthreads();
    if (t < 128) {
        float ma = red_m[0][t], mb = red_m[1][t];
        float sa = red_s[0][t], sb = red_s[1][t];
        float m = fmaxf(ma, mb);
        float s = sa * __expf(ma - m) + sb * __expf(mb - m);
        int idx = blockIdx.y * (B_ * S_) + b * S_ + n0 + t;
        pm[idx] = m;
        ps[idx] = s;
    }
}

// --------------------------- column softmax --------------------------------

__global__ void k_colstats2(const float* __restrict__ pm, const float* __restrict__ ps,
                            float* __restrict__ cmax, float* __restrict__ cinv)
{
    int i = blockIdx.x * 256 + threadIdx.x;   // 8192
    float m = -3.0e38f;
#pragma unroll
    for (int c = 0; c < 16; c++) m = fmaxf(m, pm[c * (B_ * S_) + i]);
    float sum = 0.f;
#pragma unroll
    for (int c = 0; c < 16; c++) sum += ps[c * (B_ * S_) + i] * __expf(pm[c * (B_ * S_) + i] - m);
    cmax[i] = m;
    cinv[i] = 1.0f / sum;
}

// weight = exp(L - cmax)/csum, in place; also emit bf16 copy for GEMM2
__global__ void k_softmax_norm(float4* __restrict__ L, const float4* __restrict__ cmax4,
                               const float4* __restrict__ cinv4, ushort4* __restrict__ wbf)
{
    const int64_t n4 = (int64_t)B_ * S_ * S_ / 4;
    for (int64_t i = (int64_t)blockIdx.x * blockDim.x + threadIdx.x; i < n4;
         i += (int64_t)gridDim.x * blockDim.x) {
        int b  = (int)(i >> 20);              // S_*S_/4 = 2^20 float4 per batch
        int c4 = (int)(i & 511);              // (element s)/4
        float4 x  = L[i];
        float4 cm = cmax4[b * 512 + c4];
        float4 ci = cinv4[b * 512 + c4];
        float4 w;
        w.x = __expf(x.x - cm.x) * ci.x;
        w.y = __expf(x.y - cm.y) * ci.y;
        w.z = __expf(x.z - cm.z) * ci.z;
        w.w = __expf(x.w - cm.w) * ci.w;
        L[i] = w;
        wbf[i] = (ushort4){f2bf(w.x), f2bf(w.y), f2bf(w.z), f2bf(w.w)};
    }
}

// ------------------------------- GEMM 2 ------------------------------------
// weight_sum[b] = weight[b] (2048x2048) @ src[b] -> NT with srcT [d, s]
// epilogue writes bf16 into A_cat[:, 0:1024]
__launch_bounds__(256)
__global__ void k_gemm_wsum(const ushort_t* __restrict__ Wt, const ushort_t* __restrict__ Bt,
                            ushort_t* __restrict__ acat)
{
    const int M = S_, N = D_, K = S_;
    int b = blockIdx.z;
    const ushort_t* A  = Wt + (int64_t)b * M * K;
    const ushort_t* Bm = Bt + (int64_t)b * N * K;

    __shared__ __align__(16) ushort_t sA[128 * 32], sB[128 * 32];

    int t    = threadIdx.x;
    int m0   = blockIdx.y * 128, n0 = blockIdx.x * 128;
    int wave = t >> 6, lane = t & 63;
    int wr   = (wave >> 1) * 64, wc = (wave & 1) * 64;
    int l15  = lane & 15, quad = lane >> 4;

    f32x4 acc[4][4];
#pragma unroll
    for (int i = 0; i < 4; i++)
#pragma unroll
        for (int j = 0; j < 4; j++) acc[i][j] = (f32x4){0.f, 0.f, 0.f, 0.f};

    int srow = t >> 2;
    int scol = (((t & 3) ^ ((t >> 3) & 3)) * 8);
    int slot8 = (quad ^ ((l15 >> 1) & 3)) * 8;

    const ushort_t* gA0 = A  + (int64_t)(m0 + srow) * K + scol;
    const ushort_t* gA1 = gA0 + (int64_t)64 * K;
    const ushort_t* gB0 = Bm + (int64_t)(n0 + srow) * K + scol;
    const ushort_t* gB1 = gB0 + (int64_t)64 * K;
    ushort_t* lA0 = sA + wave * 512;  ushort_t* lA1 = sA + 2048 + wave * 512;
    ushort_t* lB0 = sB + wave * 512;  ushort_t* lB1 = sB + 2048 + wave * 512;

    for (int k0 = 0; k0 < K; k0 += 32) {
        ld16(gA0, lA0);  ld16(gA1, lA1);
        ld16(gB0, lB0);  ld16(gB1, lB1);
        gA0 += 32; gA1 += 32; gB0 += 32; gB1 += 32;
        __syncthreads();

        bf16x8 af[4], bf[4];
#pragma unroll
        for (int i = 0; i < 4; i++) af[i] = *(const bf16x8*)(&sA[(wr + i * 16 + l15) * 32 + slot8]);
#pragma unroll
        for (int j = 0; j < 4; j++) bf[j] = *(const bf16x8*)(&sB[(wc + j * 16 + l15) * 32 + slot8]);
#pragma unroll
        for (int i = 0; i < 4; i++)
#pragma unroll
            for (int j = 0; j < 4; j++)
                acc[i][j] = __builtin_amdgcn_mfma_f32_16x16x32_bf16(af[i], bf[j], acc[i][j], 0, 0, 0);
        __syncthreads();
    }

#pragma unroll
    for (int i = 0; i < 4; i++) {
        int row_base = m0 + wr + i * 16 + quad * 4;
#pragma unroll
        for (int j = 0; j < 4; j++) {
            int col = n0 + wc + j * 16 + l15;
#pragma unroll
            for (int r = 0; r < 4; r++)
                acat[((int64_t)b * S_ + row_base + r) * K2 + col] = f2bf(acc[i][j][r]);
        }
    }
}

// ------------------------------- GEMM 3 ------------------------------------
// out = A_cat (8192x2048) @ W^T + bias   (NT, W row-major [1024, 2048])
__launch_bounds__(256)
__global__ void k_gemm_out(const ushort_t* __restrict__ A, const ushort_t* __restrict__ Bw,
                           const float* __restrict__ bias, float* __restrict__ out)
{
    const int N = OUTD, K = K2;

    __shared__ __align__(16) ushort_t sA[128 * 32], sB[128 * 32];

    int t    = threadIdx.x;
    int m0   = blockIdx.y * 128, n0 = blockIdx.x * 128;
    int wave = t >> 6, lane = t & 63;
    int wr   = (wave >> 1) * 64, wc = (wave & 1) * 64;
    int l15  = lane & 15, quad = lane >> 4;

    f32x4 acc[4][4];
#pragma unroll
    for (int i = 0; i < 4; i++)
#pragma unroll
        for (int j = 0; j < 4; j++) acc[i][j] = (f32x4){0.f, 0.f, 0.f, 0.f};

    int srow = t >> 2;
    int scol = (((t & 3) ^ ((t >> 3) & 3)) * 8);
    int slot8 = (quad ^ ((l15 >> 1) & 3)) * 8;

    const ushort_t* gA0 = A  + (int64_t)(m0 + srow) * K + scol;
    const ushort_t* gA1 = gA0 + (int64_t)64 * K;
    const ushort_t* gB0 = Bw + (int64_t)(n0 + srow) * K + scol;
    const ushort_t* gB1 = gB0 + (int64_t)64 * K;
    ushort_t* lA0 = sA + wave * 512;  ushort_t* lA1 = sA + 2048 + wave * 512;
    ushort_t* lB0 = sB + wave * 512;  ushort_t* lB1 = sB + 2048 + wave * 512;

    for (int k0 = 0; k0 < K; k0 += 32) {
        ld16(gA0, lA0);  ld16(gA1, lA1);
        ld16(gB0, lB0);  ld16(gB1, lB1);
        gA0 += 32; gA1 += 32; gB0 += 32; gB1 += 32;
        __syncthreads();

        bf16x8 af[4], bf[4];
#pragma unroll
        for (int i = 0; i < 4; i++) af[i] = *(const bf16x8*)(&sA[(wr + i * 16 + l15) * 32 + slot8]);
#pragma unroll
        for (int j = 0; j < 4; j++) bf[j] = *(const bf16x8*)(&sB[(wc + j * 16 + l15) * 32 + slot8]);
#pragma unroll
        for (int i = 0; i < 4; i++)
#pragma unroll
            for (int j = 0; j < 4; j++)
                acc[i][j] = __builtin_amdgcn_mfma_f32_16x16x32_bf16(af[i], bf[j], acc[i][j], 0, 0, 0);
        __syncthreads();
    }

#pragma unroll
    for (int i = 0; i < 4; i++) {
        int row_base = m0 + wr + i * 16 + quad * 4;
#pragma unroll
        for (int j = 0; j < 4; j++) {
            int col = n0 + wc + j * 16 + l15;
            float bv = bias[col];
#pragma unroll
            for (int r = 0; r < 4; r++)
                out[(int64_t)(row_base + r) * N + col] = acc[i][j][r] + bv;
        }
    }
}

// ------------------------------- launcher ----------------------------------

extern "C" void kernel_launch(void* const* d_in, const int* in_sizes, int n_in,
                              void* d_out, int out_size, void* d_ws, size_t ws_size,
                              hipStream_t stream)
{
    const float* src  = (const float*)d_in[0];
    const float* tgt  = (const float*)d_in[1];
    const float* W    = (const float*)d_in[2];
    const float* bias = (const float*)d_in[3];

    float* out = (float*)d_out;                           // [4,2048,1024]
    float* Lw  = out + (size_t)B_ * S_ * OUTD;            // [4,2048,2048] logits -> weight

    char*  ws = (char*)d_ws;
    size_t o  = 0;
    auto take = [&](size_t bytes) -> char* {
        char* p = ws + o;
        o += (bytes + 255) & ~(size_t)255;
        return p;
    };
    const size_t ELEMS = (size_t)B_ * S_ * D_;            // 8,388,608
    ushort_t* sh   = (ushort_t*)take(ELEMS * 2);          // src hi
    ushort_t* sl   = (ushort_t*)take(ELEMS * 2);          // src lo
    ushort_t* th   = (ushort_t*)take(ELEMS * 2);          // tgt hi
    ushort_t* tl   = (ushort_t*)take(ELEMS * 2);          // tgt lo
    ushort_t* sT   = (ushort_t*)take(ELEMS * 2);          // srcT bf16 [b,d,s]
    ushort_t* wbf  = (ushort_t*)take((size_t)B_ * S_ * S_ * 2);   // weight bf16
    ushort_t* acat = (ushort_t*)take((size_t)B_ * S_ * K2 * 2);   // [ws | tgt] bf16
    ushort_t* wb   = (ushort_t*)take((size_t)OUTD * K2 * 2);      // W bf16
    float*    pm   = (float*)take(16 * (size_t)B_ * S_ * 4);
    float*    ps   = (float*)take(16 * (size_t)B_ * S_ * 4);
    float*    cmax = (float*)take((size_t)B_ * S_ * 4);
    float*    cinv = (float*)take((size_t)B_ * S_ * 4);
    (void)ws_size; (void)in_sizes; (void)n_in; (void)out_size;

    k_split<<<dim3(2048), dim3(256), 0, stream>>>((const float4*)src, (const float4*)tgt,
                                                  (ushort4*)sh, (ushort4*)sl,
                                                  (ushort4*)th, (ushort4*)tl, (ushort4*)acat);
    k_wconv<<<dim3(512), dim3(256), 0, stream>>>((const float4*)W, (ushort4*)wb);
    k_transpose<<<dim3(32, 64, 4), dim3(32, 8), 0, stream>>>(src, sT);

    k_gemm_logits<<<dim3(16, 16, 4), dim3(256), 0, stream>>>(th, tl, sh, sl, Lw, pm, ps);

    k_colstats2<<<dim3(32), dim3(256), 0, stream>>>(pm, ps, cmax, cinv);
    k_softmax_norm<<<dim3(2048), dim3(256), 0, stream>>>((float4*)Lw, (const float4*)cmax,
                                                         (const float4*)cinv, (ushort4*)wbf);

    k_gemm_wsum<<<dim3(8, 16, 4), dim3(256), 0, stream>>>(wbf, sT, acat);
    k_gemm_out<<<dim3(8, 64), dim3(256), 0, stream>>>(acat, wb, bias, out);
}